// Round 10
// baseline (1540.229 us; speedup 1.0000x reference)
//
#include <hip/hip_runtime.h>
#include <float.h>

#define BB 32
#define MMv 512
#define LLv 512
#define DDv 128
#define HHv 8
#define DFFv 256
#define KNB 16
#define NLAY 2
#define NNODE (BB*MMv)       // 16384
#define TOTE  (NNODE*KNB)    // 262144 edges

typedef unsigned short ushort_t;
typedef unsigned int u32;
typedef __attribute__((ext_vector_type(8))) short bf16x8;
typedef __attribute__((ext_vector_type(4))) float f32x4;

__device__ __forceinline__ float bf2f(ushort_t u){
  union { u32 i; float f; } x; x.i = ((u32)u) << 16; return x.f;
}
__device__ __forceinline__ ushort_t f2bf(float f){
  union { u32 i; float f; } x; x.f = f;
  u32 r = x.i + 0x7FFFu + ((x.i >> 16) & 1u);   // RNE
  return (ushort_t)(r >> 16);
}
__device__ __forceinline__ float ldx(const void* p, size_t i, int f32){
  return f32 ? ((const float*)p)[i] : bf2f(((const ushort_t*)p)[i]);
}

// ---- diagnostics (fp32 output) ----
__global__ __launch_bounds__(256) void diag_fill_k(float* out, int n, float val){
  for(int i = blockIdx.x*256 + threadIdx.x; i < n; i += gridDim.x*256) out[i] = val;
}

// ---- per-input dtype detection (one block per input) ----
struct P18 { const ushort_t* p[18]; int n[18]; };
__global__ __launch_bounds__(256) void ddet_k(P18 a, int* DF){
  int i = blockIdx.x;
  const ushort_t* q = a.p[i];
  int P = min(a.n[i], 4096);
  int t = threadIdx.x;
  int r1 = 0, evenNZ = 0, oddNZ = 0;
  for(int j=t; j<P; j+=256){
    ushort_t v = q[j];
    if(((v >> 7) & 0xFF) >= 0xC0) r1 = 1;   // impossible exponent for real bf16 data
    if(v){ if(j & 1) oddNZ = 1; else evenNZ = 1; }
  }
  __shared__ int sh[3];
  if(t==0){ sh[0]=0; sh[1]=0; sh[2]=0; }
  __syncthreads();
  if(r1) atomicOr(&sh[0],1);
  if(evenNZ) atomicOr(&sh[1],1);
  if(oddNZ) atomicOr(&sh[2],1);
  __syncthreads();
  if(t==0) DF[i] = sh[0] | ((sh[1]==0) & (sh[2]!=0));
}

// ---- split-transpose: x_enc[B,L,M] -> Xhi/Xlo[B,M,L] (x ~= hi+lo, ~2^-17 rel exact) ----
__global__ __launch_bounds__(256) void split_k(const void* xe, ushort_t* Xhi,
                                               ushort_t* Xlo, const int* DF){
  __shared__ ushort_t th[32][33];
  __shared__ ushort_t tl[32][33];
  int f32 = DF[1];
  int b = blockIdx.z;
  int m0 = blockIdx.x*32, l0 = blockIdx.y*32;
  int tx = threadIdx.x, ty = threadIdx.y;   // 32 x 8
  #pragma unroll
  for(int i=0;i<4;i++){
    int l = l0+ty+8*i, m = m0+tx;
    float x = ldx(xe, (size_t)b*LLv*MMv + (size_t)l*MMv + m, f32);
    ushort_t hi = f2bf(x);
    ushort_t lo = f2bf(x - bf2f(hi));
    th[ty+8*i][tx] = hi; tl[ty+8*i][tx] = lo;
  }
  __syncthreads();
  #pragma unroll
  for(int i=0;i<4;i++){
    size_t d = (size_t)b*MMv*LLv + (size_t)(m0+ty+8*i)*LLv + l0+tx;
    Xhi[d] = th[tx][ty+8*i];
    Xlo[d] = tl[tx][ty+8*i];
  }
}

// ---- fp64 per-(b,n) column sum + reciprocal std ----
__global__ __launch_bounds__(256) void stats64_k(const void* xe, const int* DF,
                                                 double* S64, double* R64){
  int f32 = DF[1];
  int tid = blockIdx.x*256 + threadIdx.x;   // b*512+n
  int b = tid >> 9, n = tid & 511;
  size_t base = (size_t)b*LLv*MMv;
  double s = 0.0, ss = 0.0;
  for(int l=0;l<LLv;l++){
    double x = (double)ldx(xe, base + (size_t)l*MMv + n, f32);
    s += x; ss += x*x;
  }
  S64[tid] = s;
  double cov = (ss - s*s*(1.0/LLv)) * (1.0/(LLv-1));
  double sd = (cov > 0.0) ? sqrt(cov) : 0.0;
  R64[tid] = (sd > 0.0) ? (1.0/sd) : 1.0;
}

// ---- MFMA corr strip (split-bf16) + top-(K+1)-smallest selection ----
__global__ __launch_bounds__(256) void corrsel_k(const ushort_t* Xhi, const ushort_t* Xlo,
                                                 const double* S64, const double* R64,
                                                 int* nbr, const int* DF){
  __shared__ float Cs[16*516];
  __shared__ float redv[256];
  __shared__ int   redi[256];
  int f32 = DF[1];
  int strip = blockIdx.x, b = blockIdx.y;
  int m0 = strip*16;
  int t = threadIdx.x;
  int wave = t >> 6, lane = t & 63;
  int quad = lane >> 4, l16 = lane & 15;
  const ushort_t* Hb = Xhi + (size_t)b*MMv*LLv;
  const ushort_t* Lb = Xlo + (size_t)b*MMv*LLv;
  const double* Sb = S64 + b*MMv;
  const double* Rb = R64 + b*MMv;
  size_t arow = (size_t)(m0 + l16)*LLv;
  for(int ct=0; ct<8; ct++){
    int n0 = ct*64;
    size_t brow = (size_t)(n0 + wave*16 + l16)*LLv;
    f32x4 acc = {0.f,0.f,0.f,0.f};
    for(int k0=0;k0<LLv;k0+=32){
      int ko = k0 + quad*8;
      bf16x8 ah = *(const bf16x8*)&Hb[arow + ko];
      bf16x8 bh = *(const bf16x8*)&Hb[brow + ko];
      acc = __builtin_amdgcn_mfma_f32_16x16x32_bf16(ah, bh, acc, 0, 0, 0);
      if(f32){
        bf16x8 al = *(const bf16x8*)&Lb[arow + ko];
        bf16x8 bl = *(const bf16x8*)&Lb[brow + ko];
        acc = __builtin_amdgcn_mfma_f32_16x16x32_bf16(ah, bl, acc, 0, 0, 0);
        acc = __builtin_amdgcn_mfma_f32_16x16x32_bf16(al, bh, acc, 0, 0, 0);
      }
    }
    int n = n0 + wave*16 + l16;
    float sn = (float)(Sb[n]*(1.0/LLv));
    float rn = (float)Rb[n];
    #pragma unroll
    for(int r=0;r<4;r++){
      int ml = quad*4 + r;                  // C/D: row = quad*4 + reg, col = lane&15
      float cov = (acc[r] - (float)Sb[m0+ml]*sn) * (1.0f/(LLv-1));
      Cs[ml*516 + n] = cov * (float)Rb[m0+ml] * rn;
    }
  }
  __syncthreads();
  for(int rr=0; rr<4; rr++){
    int r = wave*4 + rr;
    float vals[8];
    #pragma unroll
    for(int j=0;j<8;j++) vals[j] = Cs[r*516 + lane + 64*j];
    for(int it=0; it<=KNB; it++){
      float bvv = FLT_MAX; int bi = 0x7fffffff;
      #pragma unroll
      for(int j=0;j<8;j++){
        int n = lane + 64*j;
        if(vals[j] < bvv){ bvv = vals[j]; bi = n; }
      }
      redv[t] = bvv; redi[t] = bi;
      __syncthreads();
      #pragma unroll
      for(int stride=32; stride>=1; stride>>=1){
        if(lane < stride){
          float v2 = redv[t+stride]; int i2 = redi[t+stride];
          if(v2 < redv[t] || (v2 == redv[t] && i2 < redi[t])){ redv[t]=v2; redi[t]=i2; }
        }
        __syncthreads();
      }
      int gbi = redi[wave*64];
      __syncthreads();
      int bic = min(max(gbi, 0), MMv-1);
      if(it > 0 && lane == 0) nbr[(size_t)(b*MMv + m0 + r)*KNB + it-1] = bic;
      if((gbi & 63) == lane && gbi < MMv) vals[gbi >> 6] = FLT_MAX;
    }
  }
}

// ---- graph build (all data-dependent indices clamped) ----
__global__ __launch_bounds__(256) void zero_k(int* p){
  p[blockIdx.x*256 + threadIdx.x] = 0;
}

__global__ __launch_bounds__(256) void hist_k(const int* nbr, int* cnt){
  int tid = blockIdx.x*256 + threadIdx.x;
  int b = tid >> 13;
  int col = min(max(nbr[tid], 0), MMv-1);
  atomicAdd(&cnt[b*MMv + col], 1);
}

__global__ __launch_bounds__(256) void scan_k(const int* cnt, int* off,
                                              int* cursor, float* dinv){
  __shared__ int part[256];
  int t = threadIdx.x;
  int base = t*64, s = 0;
  for(int i=0;i<64;i++) s += cnt[base+i];
  part[t] = s; __syncthreads();
  for(int st=1; st<256; st<<=1){
    int v = (t >= st) ? part[t-st] : 0;
    __syncthreads();
    part[t] += v; __syncthreads();
  }
  int run = (t > 0) ? part[t-1] : 0;
  for(int i=0;i<64;i++){
    int idx = base+i;
    off[idx] = run; cursor[idx] = run;
    run += cnt[idx];
    dinv[idx] = 1.0f/sqrtf((float)(cnt[idx]+1));   // +1 self loop
  }
  if(t == 255) off[NNODE] = run;
}

__global__ __launch_bounds__(256) void fill_k(const int* nbr, int* cursor, int* esrc){
  int tid = blockIdx.x*256 + threadIdx.x;   // edge: b*8192 + e, e = m*16+k
  int b = tid >> 13;
  int rem = tid & 8191;
  int col = min(max(nbr[tid], 0), MMv-1);
  int dst = b*MMv + col;
  int srcl = rem & 511;                      // src = e mod 512 (faithful tile() quirk)
  int pos = atomicAdd(&cursor[dst], 1);
  pos = min(max(pos, 0), TOTE-1);
  esrc[pos] = b*MMv + srcl;
}

// ---- split-bf16 MFMA GEMM: C[M,Dout] = A[M,Kd]*W[Kd,Dout] (+bias)(+relu), ~2^-17 rel exact.
// grid (Dout/128, M/64), block 256 (4 waves x 16 m-rows). W staged transposed in LDS as hi/lo.
__global__ __launch_bounds__(256) void gemm_mfma_k(const float* A, const void* W, size_t woff, int wdi,
                                                   const void* bias, int boff, int bdi,
                                                   float* C, int Kd, int Dout, int relu, const int* DF){
  __shared__ ushort_t Wh[128*136];   // [n][k] per 128-k chunk, stride 136 (2-way-free b128 reads)
  __shared__ ushort_t Wl[128*136];
  int wf32 = DF[wdi], bf32 = DF[bdi];
  int n0 = blockIdx.x*128, m0 = blockIdx.y*64;
  int t = threadIdx.x;
  int wave = t >> 6, lane = t & 63;
  int quad = lane >> 4, l16 = lane & 15;
  f32x4 acc[8];
  #pragma unroll
  for(int i=0;i<8;i++) acc[i] = (f32x4){0.f,0.f,0.f,0.f};
  const float* Arow = A + (size_t)(m0 + wave*16 + l16)*Kd;
  for(int kc = 0; kc < Kd; kc += 128){
    __syncthreads();
    for(int idx=t; idx<128*128; idx+=256){
      int k = idx >> 7, n = idx & 127;
      float w = ldx(W, woff + (size_t)(kc+k)*Dout + n0 + n, wf32);
      ushort_t hi = f2bf(w);
      Wh[n*136+k] = hi;
      Wl[n*136+k] = f2bf(w - bf2f(hi));
    }
    __syncthreads();
    #pragma unroll
    for(int ks=0; ks<4; ks++){
      const float* ap = Arow + kc + ks*32 + quad*8;
      bf16x8 ah, al;
      #pragma unroll
      for(int j=0;j<8;j++){
        float av = ap[j];
        ushort_t h = f2bf(av);
        ((ushort_t*)&ah)[j] = (short)h;
        ((ushort_t*)&al)[j] = (short)f2bf(av - bf2f(h));
      }
      #pragma unroll
      for(int nt=0; nt<8; nt++){
        bf16x8 wh = *(const bf16x8*)&Wh[(nt*16+l16)*136 + ks*32 + quad*8];
        bf16x8 wl = *(const bf16x8*)&Wl[(nt*16+l16)*136 + ks*32 + quad*8];
        acc[nt] = __builtin_amdgcn_mfma_f32_16x16x32_bf16(ah, wh, acc[nt], 0, 0, 0);
        acc[nt] = __builtin_amdgcn_mfma_f32_16x16x32_bf16(ah, wl, acc[nt], 0, 0, 0);
        acc[nt] = __builtin_amdgcn_mfma_f32_16x16x32_bf16(al, wh, acc[nt], 0, 0, 0);
      }
    }
  }
  int mbase = m0 + wave*16 + quad*4;        // C/D: row = quad*4 + reg, col = lane&15 (verified)
  #pragma unroll
  for(int nt=0; nt<8; nt++){
    int n = n0 + nt*16 + l16;
    float bv = bias ? ldx(bias, boff + n, bf32) : 0.f;
    #pragma unroll
    for(int r=0;r<4;r++){
      float v = acc[nt][r] + bv;
      if(relu) v = fmaxf(v, 0.f);
      C[(size_t)(mbase + r)*Dout + n] = v;
    }
  }
}

// ---- GCN aggregation (fp32, clamped gather; bias dtype via DF[bdi]) ----
__global__ __launch_bounds__(256) void agg_k(const float* xw, const int* off,
                                             const int* esrc, const float* dinv,
                                             const void* bias, int bdi, float* out,
                                             const int* DF){
  int f32 = DF[bdi];
  int node = blockIdx.x*4 + (threadIdx.x >> 6);
  int lane = threadIdx.x & 63;
  float dn = dinv[node];
  float a0 = dn*dn*xw[(size_t)node*DDv + 2*lane];
  float a1 = dn*dn*xw[(size_t)node*DDv + 2*lane+1];
  int e0 = min(max(off[node], 0), TOTE);
  int e1 = min(max(off[node+1], e0), TOTE);
  for(int e=e0; e<e1; e++){
    int s = min(max(esrc[e], 0), NNODE-1);
    float w = dinv[s]*dn;
    a0 = fmaf(w, xw[(size_t)s*DDv + 2*lane],   a0);
    a1 = fmaf(w, xw[(size_t)s*DDv + 2*lane+1], a1);
  }
  a0 += ldx(bias, 2*lane, f32); a1 += ldx(bias, 2*lane+1, f32);
  out[(size_t)node*DDv + 2*lane]   = fmaxf(a0, 0.f);
  out[(size_t)node*DDv + 2*lane+1] = fmaxf(a1, 0.f);
}

// ---- cross-attention per (b, head): fp32, per-thread online softmax ----
__global__ __launch_bounds__(256) void attn_k(const float* qg, const float* kg,
                                              const float* vg, float* og){
  __shared__ float Ks[512*16];
  __shared__ float Vs[512*16];
  int bh = blockIdx.x; int b = bh >> 3, hh = bh & 7;
  size_t base = (size_t)b*MMv*DDv + (size_t)hh*16;
  int t = threadIdx.x;
  for(int idx=t; idx<512*16; idx+=256){
    int kk = idx >> 4, i = idx & 15;
    Ks[idx] = kg[base + (size_t)kk*DDv + i];
    Vs[idx] = vg[base + (size_t)kk*DDv + i];
  }
  __syncthreads();
  for(int r=t; r<MMv; r+=256){
    float qr[16];
    #pragma unroll
    for(int i=0;i<16;i++) qr[i] = qg[base + (size_t)r*DDv + i];
    float m = -FLT_MAX, l = 0.f, acc[16] = {};
    for(int kk=0; kk<512; kk++){
      const float* kp = &Ks[kk*16];
      float s = 0.f;
      #pragma unroll
      for(int i=0;i<16;i++) s = fmaf(qr[i], kp[i], s);
      s *= 0.25f;
      float mn = fmaxf(m, s);
      float cold = __expf(m - mn);
      float p = __expf(s - mn);
      l = l*cold + p;
      const float* vp = &Vs[kk*16];
      #pragma unroll
      for(int i=0;i<16;i++) acc[i] = acc[i]*cold + p*vp[i];
      m = mn;
    }
    float inv = 1.0f/l;
    #pragma unroll
    for(int i=0;i<16;i++) og[base + (size_t)r*DDv + i] = acc[i]*inv;
  }
}

// ---- residual + LayerNorm: one thread per row, fp32 in/out; g/b dtype via DF ----
__global__ __launch_bounds__(256) void ln_k(const float* h, const float* delta,
                                            const void* g, int gdi, const void* bb, int bdi, int po,
                                            float* dst, const int* DF){
  int gf32 = DF[gdi], bf32 = DF[bdi];
  int row = blockIdx.x*256 + threadIdx.x;
  const float* hr = h + (size_t)row*DDv;
  const float* dr = delta + (size_t)row*DDv;
  float s = 0.f, ss = 0.f;
  for(int i=0;i<DDv;i++){
    float xv = hr[i] + dr[i];
    s += xv; ss = fmaf(xv, xv, ss);
  }
  float mu = s*(1.0f/DDv);
  float var = fmaxf(ss*(1.0f/DDv) - mu*mu, 0.f);
  float rs = 1.0f/sqrtf(var + 1e-5f);
  for(int i=0;i<DDv;i++){
    float xv = hr[i] + dr[i];
    dst[(size_t)row*DDv + i] = (xv - mu)*rs*ldx(g, po+i, gf32) + ldx(bb, po+i, bf32);
  }
}

// ---- enc -> fp32 h ----
__global__ __launch_bounds__(256) void cvt_k(const void* in, float* out, const int* DF){
  int f32 = DF[0];
  int tid = blockIdx.x*256 + threadIdx.x;
  out[tid] = ldx(in, tid, f32);
}

extern "C" void kernel_launch(void* const* d_in, const int* in_sizes, int n_in,
                              void* d_out, int out_size, void* d_ws, size_t ws_size,
                              hipStream_t stream) {
  if(n_in != 18){
    diag_fill_k<<<256, 256, 0, stream>>>((float*)d_out, out_size, 1000.0f);
    return;
  }
  const int expect[18] = {
    BB*MMv*DDv, BB*LLv*MMv, DDv*DDv, DDv, DDv*DDv, DDv,
    NLAY*DDv*DDv, NLAY*DDv*DDv, NLAY*DDv*DDv, NLAY*DDv*DDv,
    NLAY*DDv*DFFv, NLAY*DFFv, NLAY*DFFv*DDv, NLAY*DDv,
    NLAY*DDv, NLAY*DDv, NLAY*DDv, NLAY*DDv
  };
  for(int i=0;i<18;i++){
    if(in_sizes[i] != expect[i]){
      diag_fill_k<<<256, 256, 0, stream>>>((float*)d_out, out_size, 2000.0f + 10.0f*i);
      return;
    }
  }

  const void* enc  = d_in[0];
  const void* xe   = d_in[1];
  const void* c1W  = d_in[2];
  const void* c1b  = d_in[3];
  const void* c2W  = d_in[4];
  const void* c2b  = d_in[5];
  const void* Wq   = d_in[6];
  const void* Wk   = d_in[7];
  const void* Wv   = d_in[8];
  const void* Wo   = d_in[9];
  const void* W1   = d_in[10];
  const void* b1   = d_in[11];
  const void* W2   = d_in[12];
  const void* b2   = d_in[13];
  const void* ln1g = d_in[14];
  const void* ln1b = d_in[15];
  const void* ln2g = d_in[16];
  const void* ln2b = d_in[17];

  char* ws = (char*)d_ws;
  size_t o = 0;
  auto alloc = [&](size_t bytes){ size_t r = o; o = (o + bytes + 255) & ~(size_t)255; return r; };
  double* S64  = (double*)(ws + alloc((size_t)NNODE*8));
  double* R64  = (double*)(ws + alloc((size_t)NNODE*8));
  float* dinv  = (float*)(ws + alloc((size_t)NNODE*4));
  int*   cnt   = (int*)  (ws + alloc((size_t)NNODE*4));
  int*   cursor= (int*)  (ws + alloc((size_t)NNODE*4));
  int*   off   = (int*)  (ws + alloc((size_t)(NNODE+1)*4));
  int*   nbr   = (int*)  (ws + alloc((size_t)TOTE*4));
  int*   esrc  = (int*)  (ws + alloc((size_t)TOTE*4));
  int*   DF    = (int*)  (ws + alloc(256));
  const size_t ACTF = (size_t)NNODE*DDv*4;   // fp32 activation: 8.39 MB
  float* hF = (float*)(ws + alloc(ACTF));
  float* xg = (float*)(ws + alloc(ACTF));
  float* t0 = (float*)(ws + alloc(ACTF));
  float* t1 = (float*)(ws + alloc(ACTF));
  float* t2 = (float*)(ws + alloc(ACTF));    // t1+t2 contiguous -> ffn hidden fp32 [NNODE,DFF]
  float* t3 = (float*)(ws + alloc(ACTF));
  float* fb = t1;                             // 16.78 MB span; k/v dead when ffn runs
  // Xhi/Xlo (graph phase only) overlay hF..t1 — consumed by corrsel before cvt_k writes hF
  ushort_t* Xhi = (ushort_t*)hF;
  ushort_t* Xlo = Xhi + (size_t)BB*MMv*LLv;   // 16.78 MB each
  if(ws_size < o){
    diag_fill_k<<<256, 256, 0, stream>>>((float*)d_out, out_size, 3000.0f);
    return;
  }

  // ---- per-input dtype detection ----
  P18 pack;
  for(int i=0;i<18;i++){ pack.p[i] = (const ushort_t*)d_in[i]; pack.n[i] = in_sizes[i]; }
  ddet_k<<<18, 256, 0, stream>>>(pack, DF);

  // --- graph construction (split-bf16 MFMA corr + fp64 stats + selection) ---
  split_k<<<dim3(16,16,BB), dim3(32,8), 0, stream>>>(xe, Xhi, Xlo, DF);
  stats64_k<<<NNODE/256, 256, 0, stream>>>(xe, DF, S64, R64);
  corrsel_k<<<dim3(32, BB), 256, 0, stream>>>(Xhi, Xlo, S64, R64, nbr, DF);
  zero_k<<<NNODE/256, 256, 0, stream>>>(cnt);
  hist_k<<<TOTE/256, 256, 0, stream>>>(nbr, cnt);
  scan_k<<<1, 256, 0, stream>>>(cnt, off, cursor, dinv);
  fill_k<<<TOTE/256, 256, 0, stream>>>(nbr, cursor, esrc);

  // --- GCN (2 layers, fp32 activations, split-bf16 MFMA GEMMs) ---
  cvt_k<<<NNODE*DDv/256, 256, 0, stream>>>(enc, hF, DF);
  gemm_mfma_k<<<dim3(1,256), 256, 0, stream>>>(hF, c1W, 0, 2, nullptr, 0, 3, t0, DDv, DDv, 0, DF);
  agg_k<<<NNODE/4, 256, 0, stream>>>(t0, off, esrc, dinv, c1b, 3, t1, DF);
  gemm_mfma_k<<<dim3(1,256), 256, 0, stream>>>(t1, c2W, 0, 4, nullptr, 0, 5, t0, DDv, DDv, 0, DF);
  agg_k<<<NNODE/4, 256, 0, stream>>>(t0, off, esrc, dinv, c2b, 5, xg, DF);

  // --- transformer (2 layers, fp32 end-to-end; query stream = hF, kv = xg) ---
  for(int l=0; l<NLAY; l++){
    gemm_mfma_k<<<dim3(1,256), 256, 0, stream>>>(hF, Wq, (size_t)l*DDv*DDv, 6, nullptr, 0, 6, t0, DDv, DDv, 0, DF);
    gemm_mfma_k<<<dim3(1,256), 256, 0, stream>>>(xg, Wk, (size_t)l*DDv*DDv, 7, nullptr, 0, 7, t1, DDv, DDv, 0, DF);
    gemm_mfma_k<<<dim3(1,256), 256, 0, stream>>>(xg, Wv, (size_t)l*DDv*DDv, 8, nullptr, 0, 8, t2, DDv, DDv, 0, DF);
    attn_k<<<BB*HHv, 256, 0, stream>>>(t0, t1, t2, t3);
    gemm_mfma_k<<<dim3(1,256), 256, 0, stream>>>(t3, Wo, (size_t)l*DDv*DDv, 9, nullptr, 0, 9, t0, DDv, DDv, 0, DF);
    ln_k<<<NNODE/256, 256, 0, stream>>>(hF, t0, ln1g, 14, ln1b, 15, l*DDv, hF, DF);
    gemm_mfma_k<<<dim3(2,256), 256, 0, stream>>>(hF, W1, (size_t)l*DDv*DFFv, 10, b1, l*DFFv, 11, fb, DDv, DFFv, 1, DF);
    gemm_mfma_k<<<dim3(1,256), 256, 0, stream>>>(fb, W2, (size_t)l*DFFv*DDv, 12, b2, l*DDv, 13, t0, DFFv, DDv, 0, DF);
    float* dst = (l == NLAY-1) ? (float*)d_out : hF;
    ln_k<<<NNODE/256, 256, 0, stream>>>(hF, t0, ln2g, 16, ln2b, 17, l*DDv, dst, DF);
  }
}

// Round 11
// 1069.709 us; speedup vs baseline: 1.4399x; 1.4399x over previous
//
#include <hip/hip_runtime.h>
#include <float.h>

#define BB 32
#define MMv 512
#define LLv 512
#define DDv 128
#define HHv 8
#define DFFv 256
#define KNB 16
#define NLAY 2
#define NNODE (BB*MMv)       // 16384
#define TOTE  (NNODE*KNB)    // 262144 edges

typedef unsigned short ushort_t;
typedef unsigned int u32;
typedef __attribute__((ext_vector_type(8))) short bf16x8;
typedef __attribute__((ext_vector_type(4))) float f32x4;

__device__ __forceinline__ float bf2f(ushort_t u){
  union { u32 i; float f; } x; x.i = ((u32)u) << 16; return x.f;
}
__device__ __forceinline__ ushort_t f2bf(float f){
  union { u32 i; float f; } x; x.f = f;
  u32 r = x.i + 0x7FFFu + ((x.i >> 16) & 1u);   // RNE
  return (ushort_t)(r >> 16);
}
__device__ __forceinline__ float ldx(const void* p, size_t i, int f32){
  return f32 ? ((const float*)p)[i] : bf2f(((const ushort_t*)p)[i]);
}
__device__ __forceinline__ float wsum(float v){
  #pragma unroll
  for(int s=32;s;s>>=1) v += __shfl_xor(v,s);
  return v;
}

// ---- diagnostics (fp32 output) ----
__global__ __launch_bounds__(256) void diag_fill_k(float* out, int n, float val){
  for(int i = blockIdx.x*256 + threadIdx.x; i < n; i += gridDim.x*256) out[i] = val;
}

// ---- per-input dtype detection (one block per input) ----
struct P18 { const ushort_t* p[18]; int n[18]; };
__global__ __launch_bounds__(256) void ddet_k(P18 a, int* DF){
  int i = blockIdx.x;
  const ushort_t* q = a.p[i];
  int P = min(a.n[i], 4096);
  int t = threadIdx.x;
  int r1 = 0, evenNZ = 0, oddNZ = 0;
  for(int j=t; j<P; j+=256){
    ushort_t v = q[j];
    if(((v >> 7) & 0xFF) >= 0xC0) r1 = 1;   // impossible exponent for real bf16 data
    if(v){ if(j & 1) oddNZ = 1; else evenNZ = 1; }
  }
  __shared__ int sh[3];
  if(t==0){ sh[0]=0; sh[1]=0; sh[2]=0; }
  __syncthreads();
  if(r1) atomicOr(&sh[0],1);
  if(evenNZ) atomicOr(&sh[1],1);
  if(oddNZ) atomicOr(&sh[2],1);
  __syncthreads();
  if(t==0) DF[i] = sh[0] | ((sh[1]==0) & (sh[2]!=0));
}

// ---- split-transpose: x_enc[B,L,M] -> Xhi/Xlo[B,M,L] (x ~= hi+lo, ~2^-17 rel exact) ----
__global__ __launch_bounds__(256) void split_k(const void* xe, ushort_t* Xhi,
                                               ushort_t* Xlo, const int* DF){
  __shared__ ushort_t th[32][33];
  __shared__ ushort_t tl[32][33];
  int f32 = DF[1];
  int b = blockIdx.z;
  int m0 = blockIdx.x*32, l0 = blockIdx.y*32;
  int tx = threadIdx.x, ty = threadIdx.y;   // 32 x 8
  #pragma unroll
  for(int i=0;i<4;i++){
    int l = l0+ty+8*i, m = m0+tx;
    float x = ldx(xe, (size_t)b*LLv*MMv + (size_t)l*MMv + m, f32);
    ushort_t hi = f2bf(x);
    ushort_t lo = f2bf(x - bf2f(hi));
    th[ty+8*i][tx] = hi; tl[ty+8*i][tx] = lo;
  }
  __syncthreads();
  #pragma unroll
  for(int i=0;i<4;i++){
    size_t d = (size_t)b*MMv*LLv + (size_t)(m0+ty+8*i)*LLv + l0+tx;
    Xhi[d] = th[tx][ty+8*i];
    Xlo[d] = tl[tx][ty+8*i];
  }
}

// ---- per-(b,m) sum + rstd from transposed hi/lo rows: wave per row, coalesced ----
__global__ __launch_bounds__(256) void stats2_k(const ushort_t* Xhi, const ushort_t* Xlo,
                                                double* S64, double* R64){
  int row = blockIdx.x*4 + (threadIdx.x >> 6);
  int lane = threadIdx.x & 63;
  const ushort_t* Hr = Xhi + (size_t)row*LLv + lane*8;
  const ushort_t* Lr = Xlo + (size_t)row*LLv + lane*8;
  float s = 0.f, ss = 0.f;
  #pragma unroll
  for(int j=0;j<8;j++){
    float x = bf2f(Hr[j]) + bf2f(Lr[j]);
    s += x; ss = fmaf(x, x, ss);
  }
  s = wsum(s); ss = wsum(ss);
  if(lane == 0){
    S64[row] = (double)s;
    float cov = (ss - s*s*(1.0f/LLv)) * (1.0f/(LLv-1));
    float sd = (cov > 0.f) ? sqrtf(cov) : 0.f;
    R64[row] = (sd > 0.f) ? (double)(1.0f/sd) : 1.0;
  }
}

// ---- MFMA corr strip (split-bf16) + top-(K+1)-smallest selection.
// A-strip staged ONCE in LDS (kills the 8x redundant global fragment reads). ----
__global__ __launch_bounds__(256) void corrsel_k(const ushort_t* Xhi, const ushort_t* Xlo,
                                                 const double* S64, const double* R64,
                                                 int* nbr, const int* DF){
  __shared__ __attribute__((aligned(16))) ushort_t Ah[16*520];
  __shared__ __attribute__((aligned(16))) ushort_t Al[16*520];
  __shared__ float Cs[16*516];
  __shared__ float redv[256];
  __shared__ int   redi[256];
  int f32 = DF[1];
  int strip = blockIdx.x, b = blockIdx.y;
  int m0 = strip*16;
  int t = threadIdx.x;
  int wave = t >> 6, lane = t & 63;
  int quad = lane >> 4, l16 = lane & 15;
  const ushort_t* Hb = Xhi + (size_t)b*MMv*LLv;
  const ushort_t* Lb = Xlo + (size_t)b*MMv*LLv;
  for(int idx=t; idx<16*512; idx+=256){
    int mm = idx >> 9, l = idx & 511;
    Ah[mm*520 + l] = Hb[(size_t)(m0+mm)*LLv + l];
    Al[mm*520 + l] = Lb[(size_t)(m0+mm)*LLv + l];
  }
  __syncthreads();
  const double* Sb = S64 + b*MMv;
  const double* Rb = R64 + b*MMv;
  for(int ct=0; ct<8; ct++){
    int n0 = ct*64;
    size_t brow = (size_t)(n0 + wave*16 + l16)*LLv;
    f32x4 acc = {0.f,0.f,0.f,0.f};
    for(int k0=0;k0<LLv;k0+=32){
      int ko = k0 + quad*8;
      bf16x8 ah = *(const bf16x8*)&Ah[l16*520 + ko];
      bf16x8 bh = *(const bf16x8*)&Hb[brow + ko];
      acc = __builtin_amdgcn_mfma_f32_16x16x32_bf16(ah, bh, acc, 0, 0, 0);
      if(f32){
        bf16x8 al = *(const bf16x8*)&Al[l16*520 + ko];
        bf16x8 bl = *(const bf16x8*)&Lb[brow + ko];
        acc = __builtin_amdgcn_mfma_f32_16x16x32_bf16(ah, bl, acc, 0, 0, 0);
        acc = __builtin_amdgcn_mfma_f32_16x16x32_bf16(al, bh, acc, 0, 0, 0);
      }
    }
    int n = n0 + wave*16 + l16;
    float sn = (float)(Sb[n]*(1.0/LLv));
    float rn = (float)Rb[n];
    #pragma unroll
    for(int r=0;r<4;r++){
      int ml = quad*4 + r;                  // C/D: row = quad*4 + reg, col = lane&15
      float cov = (acc[r] - (float)Sb[m0+ml]*sn) * (1.0f/(LLv-1));
      Cs[ml*516 + n] = cov * (float)Rb[m0+ml] * rn;
    }
  }
  __syncthreads();
  for(int rr=0; rr<4; rr++){
    int r = wave*4 + rr;
    float vals[8];
    #pragma unroll
    for(int j=0;j<8;j++) vals[j] = Cs[r*516 + lane + 64*j];
    for(int it=0; it<=KNB; it++){
      float bvv = FLT_MAX; int bi = 0x7fffffff;
      #pragma unroll
      for(int j=0;j<8;j++){
        int n = lane + 64*j;
        if(vals[j] < bvv){ bvv = vals[j]; bi = n; }
      }
      redv[t] = bvv; redi[t] = bi;
      __syncthreads();
      #pragma unroll
      for(int stride=32; stride>=1; stride>>=1){
        if(lane < stride){
          float v2 = redv[t+stride]; int i2 = redi[t+stride];
          if(v2 < redv[t] || (v2 == redv[t] && i2 < redi[t])){ redv[t]=v2; redi[t]=i2; }
        }
        __syncthreads();
      }
      int gbi = redi[wave*64];
      __syncthreads();
      int bic = min(max(gbi, 0), MMv-1);    // clamp: bad data -> wrong answer, never a fault
      if(it > 0 && lane == 0) nbr[(size_t)(b*MMv + m0 + r)*KNB + it-1] = bic;
      if((gbi & 63) == lane && gbi < MMv) vals[gbi >> 6] = FLT_MAX;
    }
  }
}

// ---- graph build (all data-dependent indices clamped) ----
__global__ __launch_bounds__(256) void zero_k(int* p){
  p[blockIdx.x*256 + threadIdx.x] = 0;
}

__global__ __launch_bounds__(256) void hist_k(const int* nbr, int* cnt){
  int tid = blockIdx.x*256 + threadIdx.x;
  int b = tid >> 13;
  int col = min(max(nbr[tid], 0), MMv-1);
  atomicAdd(&cnt[b*MMv + col], 1);
}

__global__ __launch_bounds__(256) void scan_k(const int* cnt, int* off,
                                              int* cursor, float* dinv){
  __shared__ int part[256];
  int t = threadIdx.x;
  int base = t*64, s = 0;
  for(int i=0;i<64;i++) s += cnt[base+i];
  part[t] = s; __syncthreads();
  for(int st=1; st<256; st<<=1){
    int v = (t >= st) ? part[t-st] : 0;
    __syncthreads();
    part[t] += v; __syncthreads();
  }
  int run = (t > 0) ? part[t-1] : 0;
  for(int i=0;i<64;i++){
    int idx = base+i;
    off[idx] = run; cursor[idx] = run;
    run += cnt[idx];
    dinv[idx] = 1.0f/sqrtf((float)(cnt[idx]+1));   // +1 self loop
  }
  if(t == 255) off[NNODE] = run;
}

__global__ __launch_bounds__(256) void fill_k(const int* nbr, int* cursor, int* esrc){
  int tid = blockIdx.x*256 + threadIdx.x;   // edge: b*8192 + e, e = m*16+k
  int b = tid >> 13;
  int rem = tid & 8191;
  int col = min(max(nbr[tid], 0), MMv-1);
  int dst = b*MMv + col;
  int srcl = rem & 511;                      // src = e mod 512 (faithful tile() quirk)
  int pos = atomicAdd(&cursor[dst], 1);
  pos = min(max(pos, 0), TOTE-1);
  esrc[pos] = b*MMv + srcl;
}

// ---- fp32 GEMM (r9-validated): C = A*W (+bias)(+relu); W/bias dtype via DF ----
__global__ __launch_bounds__(256) void gemm_k(const float* A, const void* W,
                                              size_t woff, int wdi, const void* bias, int boff, int bdi,
                                              float* C, int Kd, int Dout, int relu,
                                              const int* DF){
  __shared__ float As[16*68];
  __shared__ float Ws[16*68];
  int wf32 = DF[wdi];
  int bf32 = DF[bdi];
  int m0 = blockIdx.y*64, n0 = blockIdx.x*64;
  int tx = threadIdx.x, ty = threadIdx.y;
  int t = ty*16 + tx;
  float acc[4][4] = {};
  int ar = t >> 2, ac4 = (t & 3)*4;
  int wk = t >> 4, wc4 = (t & 15)*4;
  for(int k0=0; k0<Kd; k0+=16){
    const float* ap = &A[(size_t)(m0+ar)*Kd + k0 + ac4];
    size_t wbase = woff + (size_t)(k0+wk)*Dout + n0 + wc4;
    As[(ac4+0)*68+ar] = ap[0]; As[(ac4+1)*68+ar] = ap[1];
    As[(ac4+2)*68+ar] = ap[2]; As[(ac4+3)*68+ar] = ap[3];
    Ws[wk*68+wc4+0] = ldx(W, wbase+0, wf32); Ws[wk*68+wc4+1] = ldx(W, wbase+1, wf32);
    Ws[wk*68+wc4+2] = ldx(W, wbase+2, wf32); Ws[wk*68+wc4+3] = ldx(W, wbase+3, wf32);
    __syncthreads();
    #pragma unroll
    for(int k=0;k<16;k++){
      float4 a = *(const float4*)&As[k*68 + ty*4];
      float4 w = *(const float4*)&Ws[k*68 + tx*4];
      float avr[4] = {a.x,a.y,a.z,a.w};
      float wvr[4] = {w.x,w.y,w.z,w.w};
      #pragma unroll
      for(int i=0;i<4;i++)
        #pragma unroll
        for(int j=0;j<4;j++)
          acc[i][j] = fmaf(avr[i], wvr[j], acc[i][j]);
    }
    __syncthreads();
  }
  #pragma unroll
  for(int i=0;i<4;i++){
    #pragma unroll
    for(int j=0;j<4;j++){
      int n = n0 + tx*4 + j;
      float v = acc[i][j];
      if(bias) v += ldx(bias, boff + n, bf32);
      if(relu) v = fmaxf(v, 0.f);
      C[(size_t)(m0+ty*4+i)*Dout + n] = v;
    }
  }
}

// ---- GCN aggregation (fp32, clamped gather; bias dtype via DF[bdi]) ----
__global__ __launch_bounds__(256) void agg_k(const float* xw, const int* off,
                                             const int* esrc, const float* dinv,
                                             const void* bias, int bdi, float* out,
                                             const int* DF){
  int f32 = DF[bdi];
  int node = blockIdx.x*4 + (threadIdx.x >> 6);
  int lane = threadIdx.x & 63;
  float dn = dinv[node];
  float a0 = dn*dn*xw[(size_t)node*DDv + 2*lane];
  float a1 = dn*dn*xw[(size_t)node*DDv + 2*lane+1];
  int e0 = min(max(off[node], 0), TOTE);
  int e1 = min(max(off[node+1], e0), TOTE);
  for(int e=e0; e<e1; e++){
    int s = min(max(esrc[e], 0), NNODE-1);
    float w = dinv[s]*dn;
    a0 = fmaf(w, xw[(size_t)s*DDv + 2*lane],   a0);
    a1 = fmaf(w, xw[(size_t)s*DDv + 2*lane+1], a1);
  }
  a0 += ldx(bias, 2*lane, f32); a1 += ldx(bias, 2*lane+1, f32);
  out[(size_t)node*DDv + 2*lane]   = fmaxf(a0, 0.f);
  out[(size_t)node*DDv + 2*lane+1] = fmaxf(a1, 0.f);
}

// ---- cross-attention: grid (bh*2), one row per thread, K/V in LDS ----
__global__ __launch_bounds__(256) void attn_k(const float* qg, const float* kg,
                                              const float* vg, float* og){
  __shared__ float Ks[512*16];
  __shared__ float Vs[512*16];
  int bh = blockIdx.x >> 1, rc = blockIdx.x & 1;
  int b = bh >> 3, hh = bh & 7;
  size_t base = (size_t)b*MMv*DDv + (size_t)hh*16;
  int t = threadIdx.x;
  for(int idx=t; idx<512*16; idx+=256){
    int kk = idx >> 4, i = idx & 15;
    Ks[idx] = kg[base + (size_t)kk*DDv + i];
    Vs[idx] = vg[base + (size_t)kk*DDv + i];
  }
  __syncthreads();
  int r = rc*256 + t;
  float qr[16];
  #pragma unroll
  for(int i=0;i<16;i++) qr[i] = qg[base + (size_t)r*DDv + i];
  float m = -FLT_MAX, l = 0.f, acc[16] = {};
  for(int kk=0; kk<512; kk++){
    const float* kp = &Ks[kk*16];
    float s = 0.f;
    #pragma unroll
    for(int i=0;i<16;i++) s = fmaf(qr[i], kp[i], s);
    s *= 0.25f;
    float mn = fmaxf(m, s);
    float cold = __expf(m - mn);
    float p = __expf(s - mn);
    l = l*cold + p;
    const float* vp = &Vs[kk*16];
    #pragma unroll
    for(int i=0;i<16;i++) acc[i] = acc[i]*cold + p*vp[i];
    m = mn;
  }
  float inv = 1.0f/l;
  #pragma unroll
  for(int i=0;i<16;i++) og[base + (size_t)r*DDv + i] = acc[i]*inv;
}

// ---- residual + LayerNorm: wave per row, shuffle-reduced, fp32 ----
__global__ __launch_bounds__(256) void ln_k(const float* h, const float* delta,
                                            const void* g, int gdi, const void* bb, int bdi, int po,
                                            float* dst, const int* DF){
  int gf32 = DF[gdi], bf32 = DF[bdi];
  int row = blockIdx.x*4 + (threadIdx.x >> 6);
  int lane = threadIdx.x & 63;
  const float2* hr = (const float2*)(h + (size_t)row*DDv);
  const float2* dr = (const float2*)(delta + (size_t)row*DDv);
  float2 hv = hr[lane], dv = dr[lane];
  float x0 = hv.x + dv.x, x1 = hv.y + dv.y;
  float mu = wsum(x0 + x1) * (1.0f/DDv);
  float d0 = x0 - mu, d1 = x1 - mu;
  float var = wsum(d0*d0 + d1*d1) * (1.0f/DDv);
  float rs = 1.0f/sqrtf(var + 1e-5f);
  int c0 = lane*2;
  float y0 = d0*rs*ldx(g, po+c0,   gf32) + ldx(bb, po+c0,   bf32);
  float y1 = d1*rs*ldx(g, po+c0+1, gf32) + ldx(bb, po+c0+1, bf32);
  ((float2*)(dst + (size_t)row*DDv))[lane] = make_float2(y0, y1);
}

// ---- enc -> fp32 h ----
__global__ __launch_bounds__(256) void cvt_k(const void* in, float* out, const int* DF){
  int f32 = DF[0];
  int tid = blockIdx.x*256 + threadIdx.x;
  out[tid] = ldx(in, tid, f32);
}

extern "C" void kernel_launch(void* const* d_in, const int* in_sizes, int n_in,
                              void* d_out, int out_size, void* d_ws, size_t ws_size,
                              hipStream_t stream) {
  if(n_in != 18){
    diag_fill_k<<<256, 256, 0, stream>>>((float*)d_out, out_size, 1000.0f);
    return;
  }
  const int expect[18] = {
    BB*MMv*DDv, BB*LLv*MMv, DDv*DDv, DDv, DDv*DDv, DDv,
    NLAY*DDv*DDv, NLAY*DDv*DDv, NLAY*DDv*DDv, NLAY*DDv*DDv,
    NLAY*DDv*DFFv, NLAY*DFFv, NLAY*DFFv*DDv, NLAY*DDv,
    NLAY*DDv, NLAY*DDv, NLAY*DDv, NLAY*DDv
  };
  for(int i=0;i<18;i++){
    if(in_sizes[i] != expect[i]){
      diag_fill_k<<<256, 256, 0, stream>>>((float*)d_out, out_size, 2000.0f + 10.0f*i);
      return;
    }
  }

  const void* enc  = d_in[0];
  const void* xe   = d_in[1];
  const void* c1W  = d_in[2];
  const void* c1b  = d_in[3];
  const void* c2W  = d_in[4];
  const void* c2b  = d_in[5];
  const void* Wq   = d_in[6];
  const void* Wk   = d_in[7];
  const void* Wv   = d_in[8];
  const void* Wo   = d_in[9];
  const void* W1   = d_in[10];
  const void* b1   = d_in[11];
  const void* W2   = d_in[12];
  const void* b2   = d_in[13];
  const void* ln1g = d_in[14];
  const void* ln1b = d_in[15];
  const void* ln2g = d_in[16];
  const void* ln2b = d_in[17];

  char* ws = (char*)d_ws;
  size_t o = 0;
  auto alloc = [&](size_t bytes){ size_t r = o; o = (o + bytes + 255) & ~(size_t)255; return r; };
  double* S64  = (double*)(ws + alloc((size_t)NNODE*8));
  double* R64  = (double*)(ws + alloc((size_t)NNODE*8));
  float* dinv  = (float*)(ws + alloc((size_t)NNODE*4));
  int*   cnt   = (int*)  (ws + alloc((size_t)NNODE*4));
  int*   cursor= (int*)  (ws + alloc((size_t)NNODE*4));
  int*   off   = (int*)  (ws + alloc((size_t)(NNODE+1)*4));
  int*   nbr   = (int*)  (ws + alloc((size_t)TOTE*4));
  int*   esrc  = (int*)  (ws + alloc((size_t)TOTE*4));
  int*   DF    = (int*)  (ws + alloc(256));
  const size_t ACTF = (size_t)NNODE*DDv*4;   // fp32 activation: 8.39 MB
  float* hF = (float*)(ws + alloc(ACTF));
  float* xg = (float*)(ws + alloc(ACTF));
  float* t0 = (float*)(ws + alloc(ACTF));
  float* t1 = (float*)(ws + alloc(ACTF));
  float* t2 = (float*)(ws + alloc(ACTF));    // t1+t2 contiguous -> ffn hidden fp32 [NNODE,DFF]
  float* t3 = (float*)(ws + alloc(ACTF));
  float* fb = t1;                             // 16.78 MB span; k/v dead when ffn runs
  // Xhi/Xlo (graph phase only) overlay hF..t1 — consumed by corrsel before cvt_k writes hF
  ushort_t* Xhi = (ushort_t*)hF;
  ushort_t* Xlo = Xhi + (size_t)BB*MMv*LLv;   // 16.78 MB each
  if(ws_size < o){
    diag_fill_k<<<256, 256, 0, stream>>>((float*)d_out, out_size, 3000.0f);
    return;
  }

  // ---- per-input dtype detection ----
  P18 pack;
  for(int i=0;i<18;i++){ pack.p[i] = (const ushort_t*)d_in[i]; pack.n[i] = in_sizes[i]; }
  ddet_k<<<18, 256, 0, stream>>>(pack, DF);

  // --- graph construction (split-bf16 MFMA corr + hi/lo stats + selection) ---
  split_k<<<dim3(16,16,BB), dim3(32,8), 0, stream>>>(xe, Xhi, Xlo, DF);
  stats2_k<<<NNODE/4, 256, 0, stream>>>(Xhi, Xlo, S64, R64);
  corrsel_k<<<dim3(32, BB), 256, 0, stream>>>(Xhi, Xlo, S64, R64, nbr, DF);
  zero_k<<<NNODE/256, 256, 0, stream>>>(cnt);
  hist_k<<<TOTE/256, 256, 0, stream>>>(nbr, cnt);
  scan_k<<<1, 256, 0, stream>>>(cnt, off, cursor, dinv);
  fill_k<<<TOTE/256, 256, 0, stream>>>(nbr, cursor, esrc);

  // --- GCN (2 layers, fp32) ---
  cvt_k<<<NNODE*DDv/256, 256, 0, stream>>>(enc, hF, DF);
  gemm_k<<<dim3(2,256), dim3(16,16), 0, stream>>>(hF, c1W, 0, 2, nullptr, 0, 3, t0, DDv, DDv, 0, DF);
  agg_k<<<NNODE/4, 256, 0, stream>>>(t0, off, esrc, dinv, c1b, 3, t1, DF);
  gemm_k<<<dim3(2,256), dim3(16,16), 0, stream>>>(t1, c2W, 0, 4, nullptr, 0, 5, t0, DDv, DDv, 0, DF);
  agg_k<<<NNODE/4, 256, 0, stream>>>(t0, off, esrc, dinv, c2b, 5, xg, DF);

  // --- transformer (2 layers, fp32 end-to-end; query stream = hF, kv = xg) ---
  for(int l=0; l<NLAY; l++){
    gemm_k<<<dim3(2,256), dim3(16,16), 0, stream>>>(hF, Wq, (size_t)l*DDv*DDv, 6, nullptr, 0, 6, t0, DDv, DDv, 0, DF);
    gemm_k<<<dim3(2,256), dim3(16,16), 0, stream>>>(xg, Wk, (size_t)l*DDv*DDv, 7, nullptr, 0, 7, t1, DDv, DDv, 0, DF);
    gemm_k<<<dim3(2,256), dim3(16,16), 0, stream>>>(xg, Wv, (size_t)l*DDv*DDv, 8, nullptr, 0, 8, t2, DDv, DDv, 0, DF);
    attn_k<<<BB*HHv*2, 256, 0, stream>>>(t0, t1, t2, t3);
    gemm_k<<<dim3(2,256), dim3(16,16), 0, stream>>>(t3, Wo, (size_t)l*DDv*DDv, 9, nullptr, 0, 9, t0, DDv, DDv, 0, DF);
    ln_k<<<NNODE/4, 256, 0, stream>>>(hF, t0, ln1g, 14, ln1b, 15, l*DDv, hF, DF);
    gemm_k<<<dim3(4,256), dim3(16,16), 0, stream>>>(hF, W1, (size_t)l*DDv*DFFv, 10, b1, l*DFFv, 11, fb, DDv, DFFv, 1, DF);
    gemm_k<<<dim3(2,256), dim3(16,16), 0, stream>>>(fb, W2, (size_t)l*DFFv*DDv, 12, b2, l*DDv, 13, t0, DFFv, DDv, 0, DF);
    float* dst = (l == NLAY-1) ? (float*)d_out : hF;
    ln_k<<<NNODE/4, 256, 0, stream>>>(hF, t0, ln2g, 16, ln2b, 17, l*DDv, dst, DF);
  }
}